// Round 11
// baseline (532.981 us; speedup 1.0000x reference)
//
#include <hip/hip_runtime.h>
#include <hip/hip_bf16.h>
#include <math.h>

#define AS1 __attribute__((address_space(1)))
#define AS3 __attribute__((address_space(3)))

typedef __bf16 bf16x8 __attribute__((ext_vector_type(8)));
typedef __bf16 bf16x4 __attribute__((ext_vector_type(4)));
typedef float  f32x4  __attribute__((ext_vector_type(4)));

static constexpr int   N_ROWS   = 10000;
static constexpr int   D        = 256;           // K for all GEMMs
static constexpr float INV_TAU  = 2.0f;          // 1/0.5

// gram tiling: 256x256 tiles, rows padded to 10240
static constexpr int   T_R      = 40;            // ceil(10000/256)
static constexpr int   NP       = T_R * 256;     // 10240
static constexpr float PADF     = 240.0f;        // NP - N_ROWS (exp(0)=1 each)
static constexpr int   F_TILES  = T_R * T_R;             // 1600
static constexpr int   Y_TILES  = T_R * (T_R + 1) / 2;   // 820
static constexpr int   NWGG     = 3 * F_TILES + 2 * Y_TILES;  // 6440

// proj tiling (128x128 structure)
static constexpr int   PT       = 79;

// ---------------------------------------------------------------------------
// 128x128 tile GEMM helper (projection GEMMs only). K=256, BK=64,
// single-buffer, XOR-swizzled LDS via pre-swizzled global_load_lds source.
// ---------------------------------------------------------------------------
__device__ __forceinline__ void tile_gemm_128(
    const __bf16* __restrict__ Abase, const __bf16* __restrict__ Bbase,
    char* ldsA, char* ldsB, int tid, f32x4 acc[4][4])
{
  const int l      = tid & 63;
  const int wr     = (tid >> 7) & 1;
  const int wc     = (tid >> 6) & 1;
  const int srow   = tid >> 3;
  const int schunk = tid & 7;
  const int lrow   = l & 15;
  const int lk     = l >> 4;

  for (int kt = 0; kt < 4; ++kt) {
    __syncthreads();
    const int kbase = kt * 64;
#pragma unroll
    for (int rr = 0; rr < 4; ++rr) {
      const int row = rr * 32 + srow;
      const int lc  = schunk ^ (row & 7);
      const __bf16* ga = Abase + (size_t)row * D + kbase + lc * 8;
      const __bf16* gb = Bbase + (size_t)row * D + kbase + lc * 8;
      __builtin_amdgcn_global_load_lds((const AS1 void*)ga,
          (AS3 void*)(ldsA + rr * 4096 + tid * 16), 16, 0, 0);
      __builtin_amdgcn_global_load_lds((const AS1 void*)gb,
          (AS3 void*)(ldsB + rr * 4096 + tid * 16), 16, 0, 0);
    }
    __syncthreads();
#pragma unroll
    for (int ks = 0; ks < 2; ++ks) {
      bf16x8 af[4], bfr[4];
#pragma unroll
      for (int m = 0; m < 4; ++m) {
        const int row = wr * 64 + m * 16 + lrow;
        const int off = row * 128 + ((ks * 64 + lk * 16) ^ ((row & 7) << 4));
        af[m] = *(const bf16x8*)(ldsA + off);
      }
#pragma unroll
      for (int n = 0; n < 4; ++n) {
        const int row = wc * 64 + n * 16 + lrow;
        const int off = row * 128 + ((ks * 64 + lk * 16) ^ ((row & 7) << 4));
        bfr[n] = *(const bf16x8*)(ldsB + off);
      }
#pragma unroll
      for (int m = 0; m < 4; ++m)
#pragma unroll
        for (int n = 0; n < 4; ++n)
          acc[m][n] = __builtin_amdgcn_mfma_f32_16x16x32_bf16(
              af[m], bfr[n], acc[m][n], 0, 0, 0);
    }
  }
}

// ---------------------------------------------------------------------------
// Gram kernel, m201-style 8-phase: 256x256 tile, 512 thr (8 waves, 2Mx4N,
// wave tile 128x64 = acc[8][4]). BK=64, 2x64KB LDS double buffer. Per K-step
// 4 phases, each {ds_read frags -> s_barrier -> lgkmcnt(0) -> setprio(1)
// 16 MFMA setprio(0) -> s_barrier}; B frags register-reused across the two
// m-half phases (24 ds_read_b128 per step). All 8 next-step staging loads
// issued at phase 0 with counted vmcnt(8) (never 0 mid-loop). Swizzle
// chunk^(row&7) on [256][64] tiles: 2 lanes/bank on ds_read_b128 = free.
// Fused epilogue: exp(2x) + row sums (+ col sums for mirrored tiles).
// ---------------------------------------------------------------------------
__global__ __launch_bounds__(512, 1) void gram_kernel(
    const __bf16* __restrict__ p1, const __bf16* __restrict__ p2,
    const __bf16* __restrict__ p3, float* __restrict__ S)
{
  const int bid = blockIdx.x;
  const __bf16 *P, *Q;
  float *Srow, *Scol;
  int r, c;
  if (bid < 3 * F_TILES) {
    const int job = bid / F_TILES, t = bid % F_TILES;
    r = t / T_R; c = t % T_R;
    if (job == 0)      { P = p1; Q = p2; Srow = S + 1 * NP; Scol = S + 3 * NP; }
    else if (job == 1) { P = p1; Q = p3; Srow = S + 2 * NP; Scol = nullptr; }
    else               { P = p2; Q = p3; Srow = S + 5 * NP; Scol = nullptr; }
  } else {
    const int s = bid - 3 * F_TILES;
    const int job = s / Y_TILES;
    int rem = s % Y_TILES, rr = 0, w = T_R;
    while (rem >= w) { rem -= w; ++rr; --w; }
    r = rr; c = rr + rem;                       // c >= r (upper triangle)
    const __bf16* pp = job ? p2 : p1;
    float* SS = job ? (S + 4 * NP) : (S + 0 * NP);
    P = pp; Q = pp; Srow = SS; Scol = (c > r) ? SS : nullptr;  // diag: row only
  }

  const __bf16* Abase = P + (size_t)r * 256 * D;
  const __bf16* Bbase = Q + (size_t)c * 256 * D;

  // [2 bufs][A 32K | B 32K] = 128 KiB
  __shared__ __align__(16) char lds[131072];

  const int tid  = threadIdx.x;
  const int l    = tid & 63;
  const int wr   = (tid >> 8) & 1;   // 128-row half
  const int wc   = (tid >> 6) & 3;   // 64-col quarter
  const int lrow = l & 15;
  const int lk   = l >> 4;

  // Frag read offsets at ks=0 in a [256 rows][8 chunks of 16B] tile; ks=1 is
  // off ^ 64 (chunk bit2 -> byte bit6, XOR-linear). B region offset +32768.
  int offA[8], offB[4];
#pragma unroll
  for (int m = 0; m < 8; ++m) {
    const int row = wr * 128 + m * 16 + lrow;
    offA[m] = row * 128 + ((lk ^ (row & 7)) << 4);
  }
#pragma unroll
  for (int n = 0; n < 4; ++n) {
    const int row = wc * 64 + n * 16 + lrow;
    offB[n] = 32768 + row * 128 + ((lk ^ (row & 7)) << 4);
  }

  // Staging: 2048 chunks per operand tile, 4 per thread, inverse-swizzled src
  int sdst[4];
  const __bf16 *asrc[4], *bsrc[4];
#pragma unroll
  for (int j = 0; j < 4; ++j) {
    const int p = tid + j * 512;          // 0..2047 (row*8 + chunk)
    const int row = p >> 3, pc = p & 7;
    const int sc = pc ^ (row & 7);
    sdst[j] = p * 16;
    asrc[j] = Abase + (size_t)row * D + sc * 8;
    bsrc[j] = Bbase + (size_t)row * D + sc * 8;
  }

  auto stage_all = [&](int b, int kt) {
    const int kb = kt * 64;
    char* lb = lds + b * 65536;
#pragma unroll
    for (int j = 0; j < 4; ++j)
      __builtin_amdgcn_global_load_lds((const AS1 void*)(asrc[j] + kb),
          (AS3 void*)(lb + sdst[j]), 16, 0, 0);
#pragma unroll
    for (int j = 0; j < 4; ++j)
      __builtin_amdgcn_global_load_lds((const AS1 void*)(bsrc[j] + kb),
          (AS3 void*)(lb + 32768 + sdst[j]), 16, 0, 0);
  };

  f32x4 acc[8][4];
#pragma unroll
  for (int m = 0; m < 8; ++m)
#pragma unroll
    for (int n = 0; n < 4; ++n)
#pragma unroll
      for (int q = 0; q < 4; ++q) acc[m][n][q] = 0.f;

  // phase helper: ds_read for THIS phase issued before the leading barrier
  // (overlaps other waves' previous-phase MFMA), then barrier -> lgkmcnt(0)
  // -> MFMA cluster. bfv: B frags (loaded when loadB, else reused).
  auto do_phase = [&](const char* la, int mbase, int ks, bf16x8* bfv,
                      bool loadB) {
    bf16x8 af[4];
    const int kx = ks << 6;
#pragma unroll
    for (int m = 0; m < 4; ++m)
      af[m] = *(const bf16x8*)(la + (offA[mbase + m] ^ kx));
    if (loadB) {
#pragma unroll
      for (int n = 0; n < 4; ++n)
        bfv[n] = *(const bf16x8*)(la + (offB[n] ^ kx));
    }
    __builtin_amdgcn_s_barrier();
    asm volatile("s_waitcnt lgkmcnt(0)" ::: "memory");
    __builtin_amdgcn_sched_barrier(0);
    __builtin_amdgcn_s_setprio(1);
#pragma unroll
    for (int m = 0; m < 4; ++m)
#pragma unroll
      for (int n = 0; n < 4; ++n)
        acc[mbase + m][n] = __builtin_amdgcn_mfma_f32_16x16x32_bf16(
            af[m], bfv[n], acc[mbase + m][n], 0, 0, 0);
    __builtin_amdgcn_s_setprio(0);
    __builtin_amdgcn_sched_barrier(0);
    __builtin_amdgcn_s_barrier();
  };

  stage_all(0, 0);                       // prologue: K-step 0 in flight

#pragma unroll
  for (int t = 0; t < 4; ++t) {
    const char* la = lds + (t & 1) * 65536;
    bf16x8 bf0[4], bf1[4];

    // ---- phase 0: stage t+1, wait step t, then (ks0, m0-3) + B ks0 ----
    if (t < 3) {
      stage_all((t & 1) ^ 1, t + 1);     // 8 loads for step t+1
      asm volatile("s_waitcnt vmcnt(8)" ::: "memory");  // step t landed
    } else {
      asm volatile("s_waitcnt vmcnt(0)" ::: "memory");
    }
    __builtin_amdgcn_s_barrier();        // step t visible to all waves
    __builtin_amdgcn_sched_barrier(0);
    {
      bf16x8 af[4];
#pragma unroll
      for (int m = 0; m < 4; ++m)
        af[m] = *(const bf16x8*)(la + offA[m]);
#pragma unroll
      for (int n = 0; n < 4; ++n)
        bf0[n] = *(const bf16x8*)(la + offB[n]);
      asm volatile("s_waitcnt lgkmcnt(0)" ::: "memory");
      __builtin_amdgcn_sched_barrier(0);
      __builtin_amdgcn_s_setprio(1);
#pragma unroll
      for (int m = 0; m < 4; ++m)
#pragma unroll
        for (int n = 0; n < 4; ++n)
          acc[m][n] = __builtin_amdgcn_mfma_f32_16x16x32_bf16(
              af[m], bf0[n], acc[m][n], 0, 0, 0);
      __builtin_amdgcn_s_setprio(0);
      __builtin_amdgcn_sched_barrier(0);
      __builtin_amdgcn_s_barrier();
    }
    do_phase(la, 4, 0, bf0, false);      // phase 1: (ks0, m4-7), reuse B
    do_phase(la, 0, 1, bf1, true);       // phase 2: (ks1, m0-3) + B ks1
    do_phase(la, 4, 1, bf1, false);      // phase 3: (ks1, m4-7), reuse B
    __builtin_amdgcn_sched_barrier(0);   // pin next iter's stage after barrier
  }

  // ---- epilogue: exp then row/col sums (pads are exact zeros -> exp = 1,
  // corrected by -PADF in the loss kernel) ----
#pragma unroll
  for (int m = 0; m < 8; ++m)
#pragma unroll
    for (int n = 0; n < 4; ++n)
#pragma unroll
      for (int q = 0; q < 4; ++q)
        acc[m][n][q] = __expf(acc[m][n][q] * INV_TAU);

#pragma unroll
  for (int m = 0; m < 8; ++m) {
    f32x4 v = acc[m][0] + acc[m][1] + acc[m][2] + acc[m][3];
#pragma unroll
    for (int mask = 1; mask < 16; mask <<= 1)
#pragma unroll
      for (int q = 0; q < 4; ++q) v[q] += __shfl_xor(v[q], mask, 64);
    if ((l & 15) == 0) {
      const int grow = r * 256 + wr * 128 + m * 16 + lk * 4;
#pragma unroll
      for (int q = 0; q < 4; ++q) atomicAdd(&Srow[grow + q], v[q]);
    }
  }

  if (Scol) {
#pragma unroll
    for (int n = 0; n < 4; ++n) {
      float sc = 0.f;
#pragma unroll
      for (int m = 0; m < 8; ++m)
#pragma unroll
        for (int q = 0; q < 4; ++q) sc += acc[m][n][q];
      sc += __shfl_xor(sc, 16, 64);
      sc += __shfl_xor(sc, 32, 64);
      if (l < 16) atomicAdd(&Scol[c * 256 + wc * 64 + n * 16 + l], sc);
    }
  }
}

// ---------------------------------------------------------------------------
// Projection GEMM: C = A @ B^T + bias, MODE 0: elu -> bf16, MODE 1: f32.
// ---------------------------------------------------------------------------
template <int MODE>
__global__ __launch_bounds__(256, 2) void proj_kernel(
    const __bf16* __restrict__ A, const __bf16* __restrict__ B,
    const float* __restrict__ bias, void* __restrict__ out)
{
  const int r = blockIdx.x, c = blockIdx.y;
  __shared__ __align__(16) char lds[32768];
  f32x4 acc[4][4];
#pragma unroll
  for (int m = 0; m < 4; ++m)
#pragma unroll
    for (int n = 0; n < 4; ++n)
#pragma unroll
      for (int q = 0; q < 4; ++q) acc[m][n][q] = 0.f;

  tile_gemm_128(A + (size_t)r * 128 * D, B + (size_t)c * 128 * D,
                lds, lds + 16384, threadIdx.x, acc);

  const int tid = threadIdx.x, l = tid & 63;
  const int wr = (tid >> 7) & 1, wc = (tid >> 6) & 1;
#pragma unroll
  for (int n = 0; n < 4; ++n) {
    const int gcol = c * 128 + wc * 64 + n * 16 + (l & 15);
    const float bn = bias[gcol];
#pragma unroll
    for (int m = 0; m < 4; ++m) {
#pragma unroll
      for (int q = 0; q < 4; ++q) {
        const int grow = r * 128 + wr * 64 + m * 16 + (l >> 4) * 4 + q;
        float v = acc[m][n][q] + bn;
        if (MODE == 0) {
          float o = v > 0.f ? v : (__expf(v) - 1.f);   // ELU
          ((__bf16*)out)[(size_t)grow * D + gcol] = (__bf16)o;
        } else {
          ((float*)out)[(size_t)grow * D + gcol] = v;
        }
      }
    }
  }
}

// ---------------------------------------------------------------------------
__global__ void cast_kernel(const float* __restrict__ src,
                            __bf16* __restrict__ dst, int n)
{
  int idx = (blockIdx.x * blockDim.x + threadIdx.x) * 4;
  const int stride = gridDim.x * blockDim.x * 4;
  for (; idx < n; idx += stride) {
    const float4 v = *(const float4*)(src + idx);
    bf16x4 o;
    o[0] = (__bf16)v.x; o[1] = (__bf16)v.y;
    o[2] = (__bf16)v.z; o[3] = (__bf16)v.w;
    *(bf16x4*)(dst + idx) = o;
  }
}

// one wave per row: L2-normalize; padded rows written as exact zeros
__global__ void norm_kernel(const float* __restrict__ praw,
                            __bf16* __restrict__ p)
{
  const int row = blockIdx.x * 4 + (threadIdx.x >> 6);
  const int l = threadIdx.x & 63;
  const size_t base = (size_t)row * D + l * 4;
  if (row < N_ROWS) {
    const float4 v = *(const float4*)(praw + base);
    float ss = v.x * v.x + v.y * v.y + v.z * v.z + v.w * v.w;
#pragma unroll
    for (int mask = 1; mask < 64; mask <<= 1) ss += __shfl_xor(ss, mask, 64);
    const float inv = 1.0f / fmaxf(sqrtf(ss), 1e-12f);
    bf16x4 o;
    o[0] = (__bf16)(v.x * inv); o[1] = (__bf16)(v.y * inv);
    o[2] = (__bf16)(v.z * inv); o[3] = (__bf16)(v.w * inv);
    *(bf16x4*)(p + base) = o;
  } else {
    bf16x4 o;
    o[0] = o[1] = o[2] = o[3] = (__bf16)0.0f;
    *(bf16x4*)(p + base) = o;
  }
}

// per-row diagonal terms: dg [5][NP] = exp(d11,d22,d12,d13,d23 / tau)
__global__ void diag_kernel(const __bf16* __restrict__ p1,
                            const __bf16* __restrict__ p2,
                            const __bf16* __restrict__ p3,
                            float* __restrict__ dg)
{
  const int row = blockIdx.x * 4 + (threadIdx.x >> 6);
  const int l = threadIdx.x & 63;
  if (row >= N_ROWS) return;
  const size_t base = (size_t)row * D + l * 4;
  const bf16x4 a = *(const bf16x4*)(p1 + base);
  const bf16x4 b = *(const bf16x4*)(p2 + base);
  const bf16x4 e = *(const bf16x4*)(p3 + base);
  float d11 = 0, d22 = 0, d12 = 0, d13 = 0, d23 = 0;
#pragma unroll
  for (int q = 0; q < 4; ++q) {
    const float fa = (float)a[q], fb = (float)b[q], fe = (float)e[q];
    d11 += fa * fa; d22 += fb * fb; d12 += fa * fb;
    d13 += fa * fe; d23 += fb * fe;
  }
#pragma unroll
  for (int mask = 1; mask < 64; mask <<= 1) {
    d11 += __shfl_xor(d11, mask, 64);
    d22 += __shfl_xor(d22, mask, 64);
    d12 += __shfl_xor(d12, mask, 64);
    d13 += __shfl_xor(d13, mask, 64);
    d23 += __shfl_xor(d23, mask, 64);
  }
  if (l == 0) {
    dg[0 * NP + row] = __expf(d11 * INV_TAU);
    dg[1 * NP + row] = __expf(d22 * INV_TAU);
    dg[2 * NP + row] = __expf(d12 * INV_TAU);
    dg[3 * NP + row] = __expf(d13 * INV_TAU);
    dg[4 * NP + row] = __expf(d23 * INV_TAU);
  }
}

__global__ void loss_kernel(const float* __restrict__ S,
                            const float* __restrict__ dg,
                            float* __restrict__ out)
{
  float local = 0.f;
  for (int i = blockIdx.x * blockDim.x + threadIdx.x; i < N_ROWS;
       i += gridDim.x * blockDim.x) {
    const float s11 = S[0 * NP + i] - PADF;
    const float s12 = S[1 * NP + i] - PADF;
    const float s13 = S[2 * NP + i] - PADF;
    const float s21 = S[3 * NP + i] - PADF;
    const float s22 = S[4 * NP + i] - PADF;
    const float s23 = S[5 * NP + i] - PADF;
    const float d11 = dg[0 * NP + i], d22 = dg[1 * NP + i];
    const float d12 = dg[2 * NP + i], d13 = dg[3 * NP + i];
    const float d23 = dg[4 * NP + i];
    const float den1 = s11 + s12 + s13 - d11 - d12 - d13;
    const float den2 = s22 + s21 + s23 - d22 - d12 - d23;
    local += 0.5f * (__logf(den1) + __logf(den2)) - __logf(d12);
  }
#pragma unroll
  for (int mask = 1; mask < 64; mask <<= 1) local += __shfl_xor(local, mask, 64);
  __shared__ float wsum[4];
  if ((threadIdx.x & 63) == 0) wsum[threadIdx.x >> 6] = local;
  __syncthreads();
  if (threadIdx.x == 0) {
    const float t = wsum[0] + wsum[1] + wsum[2] + wsum[3];
    atomicAdd(out, t * (1.0f / (float)N_ROWS));
  }
}

// ---------------------------------------------------------------------------
extern "C" void kernel_launch(void* const* d_in, const int* in_sizes, int n_in,
                              void* d_out, int out_size, void* d_ws,
                              size_t ws_size, hipStream_t stream)
{
  const float* z[3] = {(const float*)d_in[0], (const float*)d_in[1],
                       (const float*)d_in[2]};
  const float* W1 = (const float*)d_in[3];
  const float* b1 = (const float*)d_in[4];
  const float* W2 = (const float*)d_in[5];
  const float* b2 = (const float*)d_in[6];

  char* ws = (char*)d_ws;
  size_t off = 0;
  auto alloc = [&](size_t bytes) -> char* {
    char* p = ws + off;
    off += (bytes + 511) & ~(size_t)511;
    return p;
  };
  __bf16* pB[3];
  for (int m = 0; m < 3; ++m) pB[m] = (__bf16*)alloc((size_t)NP * D * 2);
  __bf16* w1b  = (__bf16*)alloc((size_t)D * D * 2);
  __bf16* w2b  = (__bf16*)alloc((size_t)D * D * 2);
  __bf16* zb   = (__bf16*)alloc((size_t)NP * D * 2);
  __bf16* hB   = (__bf16*)alloc((size_t)NP * D * 2);
  float*  praw = (float*) alloc((size_t)NP * D * 4);
  float*  Sv   = (float*) alloc((size_t)6 * NP * 4);
  float*  dg   = (float*) alloc((size_t)5 * NP * 4);

  hipMemsetAsync(Sv, 0, (size_t)6 * NP * 4, stream);
  hipMemsetAsync(d_out, 0, sizeof(float), stream);

  cast_kernel<<<64, 256, 0, stream>>>(W1, w1b, D * D);
  cast_kernel<<<64, 256, 0, stream>>>(W2, w2b, D * D);

  for (int m = 0; m < 3; ++m) {
    cast_kernel<<<2500, 256, 0, stream>>>(z[m], zb, N_ROWS * D);
    dim3 g(PT, 2);
    proj_kernel<0><<<g, 256, 0, stream>>>(zb, w1b, b1, (void*)hB);
    proj_kernel<1><<<g, 256, 0, stream>>>(hB, w2b, b2, (void*)praw);
    norm_kernel<<<NP / 4, 256, 0, stream>>>(praw, pB[m]);
  }

  gram_kernel<<<NWGG, 512, 0, stream>>>(pB[0], pB[1], pB[2], Sv);
  diag_kernel<<<2500, 256, 0, stream>>>(pB[0], pB[1], pB[2], dg);
  loss_kernel<<<64, 256, 0, stream>>>(Sv, dg, (float*)d_out);
}

// Round 12
// 267.810 us; speedup vs baseline: 1.9901x; 1.9901x over previous
//
#include <hip/hip_runtime.h>
#include <hip/hip_bf16.h>
#include <hip/hip_fp8.h>
#include <math.h>

#define AS1 __attribute__((address_space(1)))
#define AS3 __attribute__((address_space(3)))

typedef __bf16 bf16x8 __attribute__((ext_vector_type(8)));
typedef __bf16 bf16x4 __attribute__((ext_vector_type(4)));
typedef float  f32x4  __attribute__((ext_vector_type(4)));

static constexpr int   N_ROWS   = 10000;
static constexpr int   D        = 256;           // K for all GEMMs
static constexpr float INV_TAU  = 2.0f;          // 1/0.5

// gram tiling: 128x128 tiles, rows padded to 10112
static constexpr int   T        = 79;            // ceil(10000/128)
static constexpr int   NP       = T * 128;       // 10112
static constexpr float PADF     = 112.0f;        // NP - N_ROWS (exp(0)=1 each)
static constexpr int   SPR     = 10;             // strips per row (ceil(79/8))
static constexpr int   BPJ     = T * SPR;        // 790 strip-blocks per job
static constexpr int   NWGG    = 5 * BPJ;        // 3950

// proj tiling (128x128 structure)
static constexpr int   PT       = 79;

// ---------------------------------------------------------------------------
// 128x128 tile GEMM helper (projection GEMMs only, bf16). K=256, BK=64,
// single-buffer, XOR-swizzled LDS via pre-swizzled global_load_lds source.
// ---------------------------------------------------------------------------
__device__ __forceinline__ void tile_gemm_128(
    const __bf16* __restrict__ Abase, const __bf16* __restrict__ Bbase,
    char* ldsA, char* ldsB, int tid, f32x4 acc[4][4])
{
  const int l      = tid & 63;
  const int wr     = (tid >> 7) & 1;
  const int wc     = (tid >> 6) & 1;
  const int srow   = tid >> 3;
  const int schunk = tid & 7;
  const int lrow   = l & 15;
  const int lk     = l >> 4;

  for (int kt = 0; kt < 4; ++kt) {
    __syncthreads();
    const int kbase = kt * 64;
#pragma unroll
    for (int rr = 0; rr < 4; ++rr) {
      const int row = rr * 32 + srow;
      const int lc  = schunk ^ (row & 7);
      const __bf16* ga = Abase + (size_t)row * D + kbase + lc * 8;
      const __bf16* gb = Bbase + (size_t)row * D + kbase + lc * 8;
      __builtin_amdgcn_global_load_lds((const AS1 void*)ga,
          (AS3 void*)(ldsA + rr * 4096 + tid * 16), 16, 0, 0);
      __builtin_amdgcn_global_load_lds((const AS1 void*)gb,
          (AS3 void*)(ldsB + rr * 4096 + tid * 16), 16, 0, 0);
    }
    __syncthreads();
#pragma unroll
    for (int ks = 0; ks < 2; ++ks) {
      bf16x8 af[4], bfr[4];
#pragma unroll
      for (int m = 0; m < 4; ++m) {
        const int row = wr * 64 + m * 16 + lrow;
        const int off = row * 128 + ((ks * 64 + lk * 16) ^ ((row & 7) << 4));
        af[m] = *(const bf16x8*)(ldsA + off);
      }
#pragma unroll
      for (int n = 0; n < 4; ++n) {
        const int row = wc * 64 + n * 16 + lrow;
        const int off = row * 128 + ((ks * 64 + lk * 16) ^ ((row & 7) << 4));
        bfr[n] = *(const bf16x8*)(ldsB + off);
      }
#pragma unroll
      for (int m = 0; m < 4; ++m)
#pragma unroll
        for (int n = 0; n < 4; ++n)
          acc[m][n] = __builtin_amdgcn_mfma_f32_16x16x32_bf16(
              af[m], bfr[n], acc[m][n], 0, 0, 0);
    }
  }
}

// ---------------------------------------------------------------------------
// Gram kernel, strip-mined, FP8 (e4m3): each block owns up to 8 tiles
// (128x128) sharing one A-panel row r. A (128x256 fp8 = 32 KiB) persistent
// in LDS (staged once); B double-buffered at BK=64 (2x8 KiB). Total LDS
// 48 KiB -> 3 blocks/CU (the r9 analysis showed waves/SIMD is the binding
// constraint; fp8 halves bytes everywhere to buy the 3rd block).
// fp8 errors only perturb the exp-SUM denominators (numerator diag d12 is
// computed in bf16 by diag_kernel) -> bias ~1e-4, threshold 0.206.
// Layouts (8B slot s, even XOR masks so 16B gload_lds chunks stay intact):
//   A: byte = row*256 + ((s ^ (row&14))<<3), s = kt*8+sub*4+lk
//   B: byte = row*64  + ((s ^ (row&6 ))<<3), s = sub*4+lk
// Both achieve the 4-words/bank b64 minimum (conflict-free).
// ---------------------------------------------------------------------------
__global__ __launch_bounds__(256, 3) void gram_kernel(
    const unsigned char* __restrict__ p1, const unsigned char* __restrict__ p2,
    const unsigned char* __restrict__ p3, float* __restrict__ S)
{
  const int bid = blockIdx.x;
  const int job = bid / BPJ;
  const int t0  = bid % BPJ;
  const int r   = t0 / SPR;
  const int s   = t0 % SPR;
  int cstart = s * 8;
  const int cend = min(cstart + 8, T);

  const unsigned char *P, *Q;
  float *Srow, *Scol;
  bool sym = false;
  if (job == 0)      { P = p1; Q = p2; Srow = S + 1 * NP; Scol = S + 3 * NP; }
  else if (job == 1) { P = p1; Q = p3; Srow = S + 2 * NP; Scol = nullptr; }
  else if (job == 2) { P = p2; Q = p3; Srow = S + 5 * NP; Scol = nullptr; }
  else if (job == 3) { P = p1; Q = p1; Srow = S + 0 * NP; Scol = S + 0 * NP;
                       sym = true; cstart = max(cstart, r); }
  else               { P = p2; Q = p2; Srow = S + 4 * NP; Scol = S + 4 * NP;
                       sym = true; cstart = max(cstart, r); }
  const int len = cend - cstart;
  if (len <= 0) return;
  const int nsteps = len * 4;           // BK=64 steps per tile

  // A 32 KiB persistent | B 2 x 8 KiB double buffer = 48 KiB
  __shared__ __align__(16) char lds[49152];
  char* ldsB = lds + 32768;

  const int tid  = threadIdx.x;
  const int l    = tid & 63;
  const int wave = tid >> 6;
  const int wr   = wave >> 1;      // 64-row half
  const int wc   = wave & 1;       // 64-col half
  const int lrow = l & 15;
  const int lk   = l >> 4;

  // A/B frag read parameters
  int abase_[4], amask_[4], bbase_[4], bmask_[4];
#pragma unroll
  for (int m = 0; m < 4; ++m) {
    const int row = wr * 64 + m * 16 + lrow;
    abase_[m] = row * 256;
    amask_[m] = row & 14;
  }
#pragma unroll
  for (int n = 0; n < 4; ++n) {
    const int row = wc * 64 + n * 16 + lrow;
    bbase_[n] = row * 64;
    bmask_[n] = row & 6;
  }

  // ---- stage A panel once per strip (32 KiB = 2048 chunks, 8/thread) ----
  const unsigned char* Abase = P + (size_t)r * 128 * 256;
#pragma unroll
  for (int j = 0; j < 8; ++j) {
    const int p = tid + j * 256;          // 0..2047 (row*16 + chunk)
    const int row = p >> 4, pc = p & 15;
    __builtin_amdgcn_global_load_lds(
        (const AS1 void*)(Abase + (size_t)row * 256 +
                          ((pc ^ ((row >> 1) & 7)) << 4)),
        (AS3 void*)(lds + p * 16), 16, 0, 0);
  }

  // B staging: 8 KiB slab = 512 chunks, 2/thread, inverse-swizzled source
  auto stageB = [&](int buf, int i) {
    const int c  = cstart + (i >> 2);
    const int kb = (i & 3) * 64;          // byte offset (fp8 == 1B/elem)
    const unsigned char* B0 = Q + (size_t)c * 128 * 256 + kb;
    char* lb = ldsB + buf * 8192;
#pragma unroll
    for (int j = 0; j < 2; ++j) {
      const int p = tid + j * 256;        // 0..511 (row*4 + chunk)
      const int row = p >> 2, pc = p & 3;
      __builtin_amdgcn_global_load_lds(
          (const AS1 void*)(B0 + (size_t)row * 256 +
                            ((pc ^ ((row >> 1) & 3)) << 4)),
          (AS3 void*)(lb + p * 16), 16, 0, 0);
    }
  };
  stageB(0, 0);

  f32x4 rsum[4];
#pragma unroll
  for (int m = 0; m < 4; ++m)
#pragma unroll
    for (int q = 0; q < 4; ++q) rsum[m][q] = 0.f;

  for (int tt = 0; tt < len; ++tt) {
    f32x4 acc[4][4];
#pragma unroll
    for (int m = 0; m < 4; ++m)
#pragma unroll
      for (int n = 0; n < 4; ++n)
#pragma unroll
        for (int q = 0; q < 4; ++q) acc[m][n][q] = 0.f;

#pragma unroll
    for (int kt = 0; kt < 4; ++kt) {
      const int i = tt * 4 + kt;
      __syncthreads();                     // slab i (and A) staged & visible
      if (i + 1 < nsteps) stageB((i + 1) & 1, i + 1);
      const char* lb = ldsB + (i & 1) * 8192;
#pragma unroll
      for (int sub = 0; sub < 2; ++sub) {
        long af[4], bfr[4];
        const int sa = kt * 8 + sub * 4 + lk;   // A 8B-slot
        const int sb = sub * 4 + lk;            // B 8B-slot
#pragma unroll
        for (int m = 0; m < 4; ++m)
          af[m] = *(const long*)(lds + abase_[m] + ((sa ^ amask_[m]) << 3));
#pragma unroll
        for (int n = 0; n < 4; ++n)
          bfr[n] = *(const long*)(lb + bbase_[n] + ((sb ^ bmask_[n]) << 3));
#pragma unroll
        for (int m = 0; m < 4; ++m)
#pragma unroll
          for (int n = 0; n < 4; ++n)
            acc[m][n] = __builtin_amdgcn_mfma_f32_16x16x32_fp8_fp8(
                af[m], bfr[n], acc[m][n], 0, 0, 0);
      }
    }

    // ---- tile epilogue (runs while next B slab's loads are in flight) ----
    const int c = cstart + tt;
#pragma unroll
    for (int m = 0; m < 4; ++m)
#pragma unroll
      for (int n = 0; n < 4; ++n)
#pragma unroll
        for (int q = 0; q < 4; ++q)
          acc[m][n][q] = __expf(acc[m][n][q] * INV_TAU);

#pragma unroll
    for (int m = 0; m < 4; ++m)
      rsum[m] += acc[m][0] + acc[m][1] + acc[m][2] + acc[m][3];

    const bool docol = Scol && (!sym || c > r);
    if (docol) {
#pragma unroll
      for (int n = 0; n < 4; ++n) {
        float sc = 0.f;
#pragma unroll
        for (int m = 0; m < 4; ++m)
#pragma unroll
          for (int q = 0; q < 4; ++q) sc += acc[m][n][q];
        sc += __shfl_xor(sc, 16, 64);
        sc += __shfl_xor(sc, 32, 64);
        if (l < 16) atomicAdd(&Scol[c * 128 + wc * 64 + n * 16 + l], sc);
      }
    }
  }

  // ---- strip epilogue: row sums (one atomic set per strip) ----
#pragma unroll
  for (int m = 0; m < 4; ++m) {
#pragma unroll
    for (int mask = 1; mask < 16; mask <<= 1)
#pragma unroll
      for (int q = 0; q < 4; ++q)
        rsum[m][q] += __shfl_xor(rsum[m][q], mask, 64);
    if ((l & 15) == 0) {
      const int grow = r * 128 + wr * 64 + m * 16 + lk * 4;
#pragma unroll
      for (int q = 0; q < 4; ++q) atomicAdd(&Srow[grow + q], rsum[m][q]);
    }
  }
}

// ---------------------------------------------------------------------------
// Projection GEMM: C = A @ B^T + bias, MODE 0: elu -> bf16, MODE 1: f32.
// ---------------------------------------------------------------------------
template <int MODE>
__global__ __launch_bounds__(256, 2) void proj_kernel(
    const __bf16* __restrict__ A, const __bf16* __restrict__ B,
    const float* __restrict__ bias, void* __restrict__ out)
{
  const int r = blockIdx.x, c = blockIdx.y;
  __shared__ __align__(16) char lds[32768];
  f32x4 acc[4][4];
#pragma unroll
  for (int m = 0; m < 4; ++m)
#pragma unroll
    for (int n = 0; n < 4; ++n)
#pragma unroll
      for (int q = 0; q < 4; ++q) acc[m][n][q] = 0.f;

  tile_gemm_128(A + (size_t)r * 128 * D, B + (size_t)c * 128 * D,
                lds, lds + 16384, threadIdx.x, acc);

  const int tid = threadIdx.x, l = tid & 63;
  const int wr = (tid >> 7) & 1, wc = (tid >> 6) & 1;
#pragma unroll
  for (int n = 0; n < 4; ++n) {
    const int gcol = c * 128 + wc * 64 + n * 16 + (l & 15);
    const float bn = bias[gcol];
#pragma unroll
    for (int m = 0; m < 4; ++m) {
#pragma unroll
      for (int q = 0; q < 4; ++q) {
        const int grow = r * 128 + wr * 64 + m * 16 + (l >> 4) * 4 + q;
        float v = acc[m][n][q] + bn;
        if (MODE == 0) {
          float o = v > 0.f ? v : (__expf(v) - 1.f);   // ELU
          ((__bf16*)out)[(size_t)grow * D + gcol] = (__bf16)o;
        } else {
          ((float*)out)[(size_t)grow * D + gcol] = v;
        }
      }
    }
  }
}

// ---------------------------------------------------------------------------
__global__ void cast_kernel(const float* __restrict__ src,
                            __bf16* __restrict__ dst, int n)
{
  int idx = (blockIdx.x * blockDim.x + threadIdx.x) * 4;
  const int stride = gridDim.x * blockDim.x * 4;
  for (; idx < n; idx += stride) {
    const float4 v = *(const float4*)(src + idx);
    bf16x4 o;
    o[0] = (__bf16)v.x; o[1] = (__bf16)v.y;
    o[2] = (__bf16)v.z; o[3] = (__bf16)v.w;
    *(bf16x4*)(dst + idx) = o;
  }
}

// one wave per row: L2-normalize; emits bf16 (for diag) AND fp8 e4m3 (for
// gram); padded rows written as exact zeros in both.
__global__ void norm_kernel(const float* __restrict__ praw,
                            __bf16* __restrict__ p,
                            unsigned char* __restrict__ pf)
{
  const int row = blockIdx.x * 4 + (threadIdx.x >> 6);
  const int l = threadIdx.x & 63;
  const size_t base = (size_t)row * D + l * 4;
  if (row < N_ROWS) {
    const float4 v = *(const float4*)(praw + base);
    float ss = v.x * v.x + v.y * v.y + v.z * v.z + v.w * v.w;
#pragma unroll
    for (int mask = 1; mask < 64; mask <<= 1) ss += __shfl_xor(ss, mask, 64);
    const float inv = 1.0f / fmaxf(sqrtf(ss), 1e-12f);
    const float f0 = v.x * inv, f1 = v.y * inv, f2 = v.z * inv, f3 = v.w * inv;
    bf16x4 o;
    o[0] = (__bf16)f0; o[1] = (__bf16)f1; o[2] = (__bf16)f2; o[3] = (__bf16)f3;
    *(bf16x4*)(p + base) = o;
    const unsigned int b0 = __hip_fp8_e4m3(f0).__x;
    const unsigned int b1 = __hip_fp8_e4m3(f1).__x;
    const unsigned int b2 = __hip_fp8_e4m3(f2).__x;
    const unsigned int b3 = __hip_fp8_e4m3(f3).__x;
    *(unsigned int*)(pf + base) = b0 | (b1 << 8) | (b2 << 16) | (b3 << 24);
  } else {
    bf16x4 o;
    o[0] = o[1] = o[2] = o[3] = (__bf16)0.0f;
    *(bf16x4*)(p + base) = o;
    *(unsigned int*)(pf + base) = 0u;
  }
}

// per-row diagonal terms: dg [5][NP] = exp(d11,d22,d12,d13,d23 / tau)
__global__ void diag_kernel(const __bf16* __restrict__ p1,
                            const __bf16* __restrict__ p2,
                            const __bf16* __restrict__ p3,
                            float* __restrict__ dg)
{
  const int row = blockIdx.x * 4 + (threadIdx.x >> 6);
  const int l = threadIdx.x & 63;
  if (row >= N_ROWS) return;
  const size_t base = (size_t)row * D + l * 4;
  const bf16x4 a = *(const bf16x4*)(p1 + base);
  const bf16x4 b = *(const bf16x4*)(p2 + base);
  const bf16x4 e = *(const bf16x4*)(p3 + base);
  float d11 = 0, d22 = 0, d12 = 0, d13 = 0, d23 = 0;
#pragma unroll
  for (int q = 0; q < 4; ++q) {
    const float fa = (float)a[q], fb = (float)b[q], fe = (float)e[q];
    d11 += fa * fa; d22 += fb * fb; d12 += fa * fb;
    d13 += fa * fe; d23 += fb * fe;
  }
#pragma unroll
  for (int mask = 1; mask < 64; mask <<= 1) {
    d11 += __shfl_xor(d11, mask, 64);
    d22 += __shfl_xor(d22, mask, 64);
    d12 += __shfl_xor(d12, mask, 64);
    d13 += __shfl_xor(d13, mask, 64);
    d23 += __shfl_xor(d23, mask, 64);
  }
  if (l == 0) {
    dg[0 * NP + row] = __expf(d11 * INV_TAU);
    dg[1 * NP + row] = __expf(d22 * INV_TAU);
    dg[2 * NP + row] = __expf(d12 * INV_TAU);
    dg[3 * NP + row] = __expf(d13 * INV_TAU);
    dg[4 * NP + row] = __expf(d23 * INV_TAU);
  }
}

__global__ void loss_kernel(const float* __restrict__ S,
                            const float* __restrict__ dg,
                            float* __restrict__ out)
{
  float local = 0.f;
  for (int i = blockIdx.x * blockDim.x + threadIdx.x; i < N_ROWS;
       i += gridDim.x * blockDim.x) {
    const float s11 = S[0 * NP + i] - PADF;
    const float s12 = S[1 * NP + i] - PADF;
    const float s13 = S[2 * NP + i] - PADF;
    const float s21 = S[3 * NP + i] - PADF;
    const float s22 = S[4 * NP + i] - PADF;
    const float s23 = S[5 * NP + i] - PADF;
    const float d11 = dg[0 * NP + i], d22 = dg[1 * NP + i];
    const float d12 = dg[2 * NP + i], d13 = dg[3 * NP + i];
    const float d23 = dg[4 * NP + i];
    const float den1 = s11 + s12 + s13 - d11 - d12 - d13;
    const float den2 = s22 + s21 + s23 - d22 - d12 - d23;
    local += 0.5f * (__logf(den1) + __logf(den2)) - __logf(d12);
  }
#pragma unroll
  for (int mask = 1; mask < 64; mask <<= 1) local += __shfl_xor(local, mask, 64);
  __shared__ float wsum[4];
  if ((threadIdx.x & 63) == 0) wsum[threadIdx.x >> 6] = local;
  __syncthreads();
  if (threadIdx.x == 0) {
    const float t = wsum[0] + wsum[1] + wsum[2] + wsum[3];
    atomicAdd(out, t * (1.0f / (float)N_ROWS));
  }
}

// ---------------------------------------------------------------------------
extern "C" void kernel_launch(void* const* d_in, const int* in_sizes, int n_in,
                              void* d_out, int out_size, void* d_ws,
                              size_t ws_size, hipStream_t stream)
{
  const float* z[3] = {(const float*)d_in[0], (const float*)d_in[1],
                       (const float*)d_in[2]};
  const float* W1 = (const float*)d_in[3];
  const float* b1 = (const float*)d_in[4];
  const float* W2 = (const float*)d_in[5];
  const float* b2 = (const float*)d_in[6];

  char* ws = (char*)d_ws;
  size_t off = 0;
  auto alloc = [&](size_t bytes) -> char* {
    char* p = ws + off;
    off += (bytes + 511) & ~(size_t)511;
    return p;
  };
  __bf16* pB[3];
  unsigned char* pF[3];
  for (int m = 0; m < 3; ++m) pB[m] = (__bf16*)alloc((size_t)NP * D * 2);
  for (int m = 0; m < 3; ++m) pF[m] = (unsigned char*)alloc((size_t)NP * D);
  __bf16* w1b  = (__bf16*)alloc((size_t)D * D * 2);
  __bf16* w2b  = (__bf16*)alloc((size_t)D * D * 2);
  __bf16* zb   = (__bf16*)alloc((size_t)NP * D * 2);
  __bf16* hB   = (__bf16*)alloc((size_t)NP * D * 2);
  float*  praw = (float*) alloc((size_t)NP * D * 4);
  float*  Sv   = (float*) alloc((size_t)6 * NP * 4);
  float*  dg   = (float*) alloc((size_t)5 * NP * 4);

  hipMemsetAsync(Sv, 0, (size_t)6 * NP * 4, stream);
  hipMemsetAsync(d_out, 0, sizeof(float), stream);

  cast_kernel<<<64, 256, 0, stream>>>(W1, w1b, D * D);
  cast_kernel<<<64, 256, 0, stream>>>(W2, w2b, D * D);

  for (int m = 0; m < 3; ++m) {
    cast_kernel<<<2500, 256, 0, stream>>>(z[m], zb, N_ROWS * D);
    dim3 g(PT, 2);
    proj_kernel<0><<<g, 256, 0, stream>>>(zb, w1b, b1, (void*)hB);
    proj_kernel<1><<<g, 256, 0, stream>>>(hB, w2b, b2, (void*)praw);
    norm_kernel<<<NP / 4, 256, 0, stream>>>(praw, pB[m], pF[m]);
  }

  gram_kernel<<<NWGG, 256, 0, stream>>>(pF[0], pF[1], pF[2], Sv);
  diag_kernel<<<2500, 256, 0, stream>>>(pB[0], pB[1], pB[2], dg);
  loss_kernel<<<64, 256, 0, stream>>>(Sv, dg, (float*)d_out);
}

// Round 13
// 248.813 us; speedup vs baseline: 2.1421x; 1.0764x over previous
//
#include <hip/hip_runtime.h>
#include <hip/hip_bf16.h>
#include <hip/hip_fp8.h>
#include <math.h>

#define AS1 __attribute__((address_space(1)))
#define AS3 __attribute__((address_space(3)))

typedef __bf16 bf16x8 __attribute__((ext_vector_type(8)));
typedef __bf16 bf16x4 __attribute__((ext_vector_type(4)));
typedef float  f32x4  __attribute__((ext_vector_type(4)));
typedef long   longx2 __attribute__((ext_vector_type(2)));

static constexpr int   N_ROWS   = 10000;
static constexpr int   D        = 256;           // K for all GEMMs
static constexpr float INV_TAU  = 2.0f;          // 1/0.5

// gram tiling: 128x128 tiles, rows padded to 10112
static constexpr int   T        = 79;            // ceil(10000/128)
static constexpr int   NP       = T * 128;       // 10112
static constexpr float PADF     = 112.0f;        // NP - N_ROWS (exp(0)=1 each)
static constexpr int   SPR     = 10;             // strips per row (ceil(79/8))
static constexpr int   BPJ     = T * SPR;        // 790 strip-blocks per job
static constexpr int   NWGG    = 5 * BPJ;        // 3950

// proj tiling (128x128 structure)
static constexpr int   PT       = 79;

// ---------------------------------------------------------------------------
// 128x128 tile GEMM helper (projection GEMMs only, bf16). K=256, BK=64,
// single-buffer, XOR-swizzled LDS via pre-swizzled global_load_lds source.
// ---------------------------------------------------------------------------
__device__ __forceinline__ void tile_gemm_128(
    const __bf16* __restrict__ Abase, const __bf16* __restrict__ Bbase,
    char* ldsA, char* ldsB, int tid, f32x4 acc[4][4])
{
  const int l      = tid & 63;
  const int wr     = (tid >> 7) & 1;
  const int wc     = (tid >> 6) & 1;
  const int srow   = tid >> 3;
  const int schunk = tid & 7;
  const int lrow   = l & 15;
  const int lk     = l >> 4;

  for (int kt = 0; kt < 4; ++kt) {
    __syncthreads();
    const int kbase = kt * 64;
#pragma unroll
    for (int rr = 0; rr < 4; ++rr) {
      const int row = rr * 32 + srow;
      const int lc  = schunk ^ (row & 7);
      const __bf16* ga = Abase + (size_t)row * D + kbase + lc * 8;
      const __bf16* gb = Bbase + (size_t)row * D + kbase + lc * 8;
      __builtin_amdgcn_global_load_lds((const AS1 void*)ga,
          (AS3 void*)(ldsA + rr * 4096 + tid * 16), 16, 0, 0);
      __builtin_amdgcn_global_load_lds((const AS1 void*)gb,
          (AS3 void*)(ldsB + rr * 4096 + tid * 16), 16, 0, 0);
    }
    __syncthreads();
#pragma unroll
    for (int ks = 0; ks < 2; ++ks) {
      bf16x8 af[4], bfr[4];
#pragma unroll
      for (int m = 0; m < 4; ++m) {
        const int row = wr * 64 + m * 16 + lrow;
        const int off = row * 128 + ((ks * 64 + lk * 16) ^ ((row & 7) << 4));
        af[m] = *(const bf16x8*)(ldsA + off);
      }
#pragma unroll
      for (int n = 0; n < 4; ++n) {
        const int row = wc * 64 + n * 16 + lrow;
        const int off = row * 128 + ((ks * 64 + lk * 16) ^ ((row & 7) << 4));
        bfr[n] = *(const bf16x8*)(ldsB + off);
      }
#pragma unroll
      for (int m = 0; m < 4; ++m)
#pragma unroll
        for (int n = 0; n < 4; ++n)
          acc[m][n] = __builtin_amdgcn_mfma_f32_16x16x32_bf16(
              af[m], bfr[n], acc[m][n], 0, 0, 0);
    }
  }
}

// ---------------------------------------------------------------------------
// Gram kernel, strip-mined, FP8 (e4m3), b128 fragment reads.
// A (128x256 fp8 = 32 KiB) persistent in LDS; B double-buffered at BK=64
// (2x8 KiB); 48 KiB total -> 3 blocks/CU.
// k-permutation trick: MFMA sub-step sub, lane lk consumes global 8B-slot
// (2*lk + sub) of each 64-elem k-group -- applied to BOTH A and B, so the
// dot product is unchanged, and one ds_read_b128 per fragment delivers both
// sub-steps (low/high 8B). This restores the proven zero-conflict b128
// access pattern (r12's b64 reads caused 2.56e7 bank conflicts: 8B grain
// can only hit 16 aligned bank-pairs).
// Layouts: A LDS [row][16 x 16B chunk], chunk swizzle c^((row>>1)&7);
//          B LDS [row][4 x 16B chunk],  chunk swizzle c^((row>>1)&3).
// ---------------------------------------------------------------------------
__global__ __launch_bounds__(256, 3) void gram_kernel(
    const unsigned char* __restrict__ p1, const unsigned char* __restrict__ p2,
    const unsigned char* __restrict__ p3, float* __restrict__ S)
{
  const int bid = blockIdx.x;
  const int job = bid / BPJ;
  const int t0  = bid % BPJ;
  const int r   = t0 / SPR;
  const int s   = t0 % SPR;
  int cstart = s * 8;
  const int cend = min(cstart + 8, T);

  const unsigned char *P, *Q;
  float *Srow, *Scol;
  bool sym = false;
  if (job == 0)      { P = p1; Q = p2; Srow = S + 1 * NP; Scol = S + 3 * NP; }
  else if (job == 1) { P = p1; Q = p3; Srow = S + 2 * NP; Scol = nullptr; }
  else if (job == 2) { P = p2; Q = p3; Srow = S + 5 * NP; Scol = nullptr; }
  else if (job == 3) { P = p1; Q = p1; Srow = S + 0 * NP; Scol = S + 0 * NP;
                       sym = true; cstart = max(cstart, r); }
  else               { P = p2; Q = p2; Srow = S + 4 * NP; Scol = S + 4 * NP;
                       sym = true; cstart = max(cstart, r); }
  const int len = cend - cstart;
  if (len <= 0) return;
  const int nsteps = len * 4;           // BK=64 steps per tile

  // A 32 KiB persistent | B 2 x 8 KiB double buffer = 48 KiB
  __shared__ __align__(16) char lds[49152];
  char* ldsB = lds + 32768;

  const int tid  = threadIdx.x;
  const int l    = tid & 63;
  const int wave = tid >> 6;
  const int wr   = wave >> 1;      // 64-row half
  const int wc   = wave & 1;       // 64-col half
  const int lrow = l & 15;
  const int lk   = l >> 4;

  // Hoisted b128 read offsets.
  // A: chunk c = kt*4+lk, byte = row*256 + ((c ^ ((row>>1)&7))<<4)
  int offA[4][4];                  // [kt][m]
#pragma unroll
  for (int m = 0; m < 4; ++m) {
    const int row = wr * 64 + m * 16 + lrow;
    const int swz = (row >> 1) & 7;
#pragma unroll
    for (int kt = 0; kt < 4; ++kt)
      offA[kt][m] = row * 256 + (((kt * 4 + lk) ^ swz) << 4);
  }
  // B: chunk lk, byte = row*64 + ((lk ^ ((row>>1)&3))<<4)
  int offB[4];
#pragma unroll
  for (int n = 0; n < 4; ++n) {
    const int row = wc * 64 + n * 16 + lrow;
    offB[n] = row * 64 + ((lk ^ ((row >> 1) & 3)) << 4);
  }

  // ---- stage A panel once per strip (32 KiB = 2048 chunks, 8/thread) ----
  const unsigned char* Abase = P + (size_t)r * 128 * 256;
#pragma unroll
  for (int j = 0; j < 8; ++j) {
    const int p = tid + j * 256;          // 0..2047 (row*16 + chunk)
    const int row = p >> 4, pc = p & 15;
    __builtin_amdgcn_global_load_lds(
        (const AS1 void*)(Abase + (size_t)row * 256 +
                          ((pc ^ ((row >> 1) & 7)) << 4)),
        (AS3 void*)(lds + p * 16), 16, 0, 0);
  }

  // B staging: 8 KiB slab = 512 chunks, 2/thread, inverse-swizzled source
  auto stageB = [&](int buf, int i) {
    const int c  = cstart + (i >> 2);
    const int kb = (i & 3) * 64;          // byte offset (fp8 == 1B/elem)
    const unsigned char* B0 = Q + (size_t)c * 128 * 256 + kb;
    char* lb = ldsB + buf * 8192;
#pragma unroll
    for (int j = 0; j < 2; ++j) {
      const int p = tid + j * 256;        // 0..511 (row*4 + chunk)
      const int row = p >> 2, pc = p & 3;
      __builtin_amdgcn_global_load_lds(
          (const AS1 void*)(B0 + (size_t)row * 256 +
                            ((pc ^ ((row >> 1) & 3)) << 4)),
          (AS3 void*)(lb + p * 16), 16, 0, 0);
    }
  };
  stageB(0, 0);

  f32x4 rsum[4];
#pragma unroll
  for (int m = 0; m < 4; ++m)
#pragma unroll
    for (int q = 0; q < 4; ++q) rsum[m][q] = 0.f;

  for (int tt = 0; tt < len; ++tt) {
    f32x4 acc[4][4];
#pragma unroll
    for (int m = 0; m < 4; ++m)
#pragma unroll
      for (int n = 0; n < 4; ++n)
#pragma unroll
        for (int q = 0; q < 4; ++q) acc[m][n][q] = 0.f;

#pragma unroll
    for (int kt = 0; kt < 4; ++kt) {
      const int i = tt * 4 + kt;
      __syncthreads();                     // slab i (and A) staged & visible
      if (i + 1 < nsteps) stageB((i + 1) & 1, i + 1);
      const char* lb = ldsB + (i & 1) * 8192;
      longx2 af[4], bfr[4];
#pragma unroll
      for (int m = 0; m < 4; ++m)
        af[m] = *(const longx2*)(lds + offA[kt][m]);
#pragma unroll
      for (int n = 0; n < 4; ++n)
        bfr[n] = *(const longx2*)(lb + offB[n]);
      // sub-step 0: low 8B (global slot 2lk) ; sub-step 1: high 8B (2lk+1)
#pragma unroll
      for (int m = 0; m < 4; ++m)
#pragma unroll
        for (int n = 0; n < 4; ++n)
          acc[m][n] = __builtin_amdgcn_mfma_f32_16x16x32_fp8_fp8(
              af[m][0], bfr[n][0], acc[m][n], 0, 0, 0);
#pragma unroll
      for (int m = 0; m < 4; ++m)
#pragma unroll
        for (int n = 0; n < 4; ++n)
          acc[m][n] = __builtin_amdgcn_mfma_f32_16x16x32_fp8_fp8(
              af[m][1], bfr[n][1], acc[m][n], 0, 0, 0);
    }

    // ---- tile epilogue (runs while next B slab's loads are in flight) ----
    const int c = cstart + tt;
#pragma unroll
    for (int m = 0; m < 4; ++m)
#pragma unroll
      for (int n = 0; n < 4; ++n)
#pragma unroll
        for (int q = 0; q < 4; ++q)
          acc[m][n][q] = __expf(acc[m][n][q] * INV_TAU);

#pragma unroll
    for (int m = 0; m < 4; ++m)
      rsum[m] += acc[m][0] + acc[m][1] + acc[m][2] + acc[m][3];

    const bool docol = Scol && (!sym || c > r);
    if (docol) {
#pragma unroll
      for (int n = 0; n < 4; ++n) {
        float sc = 0.f;
#pragma unroll
        for (int m = 0; m < 4; ++m)
#pragma unroll
          for (int q = 0; q < 4; ++q) sc += acc[m][n][q];
        sc += __shfl_xor(sc, 16, 64);
        sc += __shfl_xor(sc, 32, 64);
        if (l < 16) atomicAdd(&Scol[c * 128 + wc * 64 + n * 16 + l], sc);
      }
    }
  }

  // ---- strip epilogue: row sums (one atomic set per strip) ----
#pragma unroll
  for (int m = 0; m < 4; ++m) {
#pragma unroll
    for (int mask = 1; mask < 16; mask <<= 1)
#pragma unroll
      for (int q = 0; q < 4; ++q)
        rsum[m][q] += __shfl_xor(rsum[m][q], mask, 64);
    if ((l & 15) == 0) {
      const int grow = r * 128 + wr * 64 + m * 16 + lk * 4;
#pragma unroll
      for (int q = 0; q < 4; ++q) atomicAdd(&Srow[grow + q], rsum[m][q]);
    }
  }
}

// ---------------------------------------------------------------------------
// Projection GEMM: C = A @ B^T + bias, MODE 0: elu -> bf16, MODE 1: f32.
// ---------------------------------------------------------------------------
template <int MODE>
__global__ __launch_bounds__(256, 2) void proj_kernel(
    const __bf16* __restrict__ A, const __bf16* __restrict__ B,
    const float* __restrict__ bias, void* __restrict__ out)
{
  const int r = blockIdx.x, c = blockIdx.y;
  __shared__ __align__(16) char lds[32768];
  f32x4 acc[4][4];
#pragma unroll
  for (int m = 0; m < 4; ++m)
#pragma unroll
    for (int n = 0; n < 4; ++n)
#pragma unroll
      for (int q = 0; q < 4; ++q) acc[m][n][q] = 0.f;

  tile_gemm_128(A + (size_t)r * 128 * D, B + (size_t)c * 128 * D,
                lds, lds + 16384, threadIdx.x, acc);

  const int tid = threadIdx.x, l = tid & 63;
  const int wr = (tid >> 7) & 1, wc = (tid >> 6) & 1;
#pragma unroll
  for (int n = 0; n < 4; ++n) {
    const int gcol = c * 128 + wc * 64 + n * 16 + (l & 15);
    const float bn = bias[gcol];
#pragma unroll
    for (int m = 0; m < 4; ++m) {
#pragma unroll
      for (int q = 0; q < 4; ++q) {
        const int grow = r * 128 + wr * 64 + m * 16 + (l >> 4) * 4 + q;
        float v = acc[m][n][q] + bn;
        if (MODE == 0) {
          float o = v > 0.f ? v : (__expf(v) - 1.f);   // ELU
          ((__bf16*)out)[(size_t)grow * D + gcol] = (__bf16)o;
        } else {
          ((float*)out)[(size_t)grow * D + gcol] = v;
        }
      }
    }
  }
}

// ---------------------------------------------------------------------------
__global__ void cast_kernel(const float* __restrict__ src,
                            __bf16* __restrict__ dst, int n)
{
  int idx = (blockIdx.x * blockDim.x + threadIdx.x) * 4;
  const int stride = gridDim.x * blockDim.x * 4;
  for (; idx < n; idx += stride) {
    const float4 v = *(const float4*)(src + idx);
    bf16x4 o;
    o[0] = (__bf16)v.x; o[1] = (__bf16)v.y;
    o[2] = (__bf16)v.z; o[3] = (__bf16)v.w;
    *(bf16x4*)(dst + idx) = o;
  }
}

// one wave per row: L2-normalize; emits bf16 (for diag) AND fp8 e4m3 (for
// gram); padded rows written as exact zeros in both.
__global__ void norm_kernel(const float* __restrict__ praw,
                            __bf16* __restrict__ p,
                            unsigned char* __restrict__ pf)
{
  const int row = blockIdx.x * 4 + (threadIdx.x >> 6);
  const int l = threadIdx.x & 63;
  const size_t base = (size_t)row * D + l * 4;
  if (row < N_ROWS) {
    const float4 v = *(const float4*)(praw + base);
    float ss = v.x * v.x + v.y * v.y + v.z * v.z + v.w * v.w;
#pragma unroll
    for (int mask = 1; mask < 64; mask <<= 1) ss += __shfl_xor(ss, mask, 64);
    const float inv = 1.0f / fmaxf(sqrtf(ss), 1e-12f);
    const float f0 = v.x * inv, f1 = v.y * inv, f2 = v.z * inv, f3 = v.w * inv;
    bf16x4 o;
    o[0] = (__bf16)f0; o[1] = (__bf16)f1; o[2] = (__bf16)f2; o[3] = (__bf16)f3;
    *(bf16x4*)(p + base) = o;
    const unsigned int b0 = __hip_fp8_e4m3(f0).__x;
    const unsigned int b1 = __hip_fp8_e4m3(f1).__x;
    const unsigned int b2 = __hip_fp8_e4m3(f2).__x;
    const unsigned int b3 = __hip_fp8_e4m3(f3).__x;
    *(unsigned int*)(pf + base) = b0 | (b1 << 8) | (b2 << 16) | (b3 << 24);
  } else {
    bf16x4 o;
    o[0] = o[1] = o[2] = o[3] = (__bf16)0.0f;
    *(bf16x4*)(p + base) = o;
    *(unsigned int*)(pf + base) = 0u;
  }
}

// per-row diagonal terms: dg [5][NP] = exp(d11,d22,d12,d13,d23 / tau)
__global__ void diag_kernel(const __bf16* __restrict__ p1,
                            const __bf16* __restrict__ p2,
                            const __bf16* __restrict__ p3,
                            float* __restrict__ dg)
{
  const int row = blockIdx.x * 4 + (threadIdx.x >> 6);
  const int l = threadIdx.x & 63;
  if (row >= N_ROWS) return;
  const size_t base = (size_t)row * D + l * 4;
  const bf16x4 a = *(const bf16x4*)(p1 + base);
  const bf16x4 b = *(const bf16x4*)(p2 + base);
  const bf16x4 e = *(const bf16x4*)(p3 + base);
  float d11 = 0, d22 = 0, d12 = 0, d13 = 0, d23 = 0;
#pragma unroll
  for (int q = 0; q < 4; ++q) {
    const float fa = (float)a[q], fb = (float)b[q], fe = (float)e[q];
    d11 += fa * fa; d22 += fb * fb; d12 += fa * fb;
    d13 += fa * fe; d23 += fb * fe;
  }
#pragma unroll
  for (int mask = 1; mask < 64; mask <<= 1) {
    d11 += __shfl_xor(d11, mask, 64);
    d22 += __shfl_xor(d22, mask, 64);
    d12 += __shfl_xor(d12, mask, 64);
    d13 += __shfl_xor(d13, mask, 64);
    d23 += __shfl_xor(d23, mask, 64);
  }
  if (l == 0) {
    dg[0 * NP + row] = __expf(d11 * INV_TAU);
    dg[1 * NP + row] = __expf(d22 * INV_TAU);
    dg[2 * NP + row] = __expf(d12 * INV_TAU);
    dg[3 * NP + row] = __expf(d13 * INV_TAU);
    dg[4 * NP + row] = __expf(d23 * INV_TAU);
  }
}

__global__ void loss_kernel(const float* __restrict__ S,
                            const float* __restrict__ dg,
                            float* __restrict__ out)
{
  float local = 0.f;
  for (int i = blockIdx.x * blockDim.x + threadIdx.x; i < N_ROWS;
       i += gridDim.x * blockDim.x) {
    const float s11 = S[0 * NP + i] - PADF;
    const float s12 = S[1 * NP + i] - PADF;
    const float s13 = S[2 * NP + i] - PADF;
    const float s21 = S[3 * NP + i] - PADF;
    const float s22 = S[4 * NP + i] - PADF;
    const float s23 = S[5 * NP + i] - PADF;
    const float d11 = dg[0 * NP + i], d22 = dg[1 * NP + i];
    const float d12 = dg[2 * NP + i], d13 = dg[3 * NP + i];
    const float d23 = dg[4 * NP + i];
    const float den1 = s11 + s12 + s13 - d11 - d12 - d13;
    const float den2 = s22 + s21 + s23 - d22 - d12 - d23;
    local += 0.5f * (__logf(den1) + __logf(den2)) - __logf(d12);
  }
#pragma unroll
  for (int mask = 1; mask < 64; mask <<= 1) local += __shfl_xor(local, mask, 64);
  __shared__ float wsum[4];
  if ((threadIdx.x & 63) == 0) wsum[threadIdx.x >> 6] = local;
  __syncthreads();
  if (threadIdx.x == 0) {
    const float t = wsum[0] + wsum[1] + wsum[2] + wsum[3];
    atomicAdd(out, t * (1.0f / (float)N_ROWS));
  }
}

// ---------------------------------------------------------------------------
extern "C" void kernel_launch(void* const* d_in, const int* in_sizes, int n_in,
                              void* d_out, int out_size, void* d_ws,
                              size_t ws_size, hipStream_t stream)
{
  const float* z[3] = {(const float*)d_in[0], (const float*)d_in[1],
                       (const float*)d_in[2]};
  const float* W1 = (const float*)d_in[3];
  const float* b1 = (const float*)d_in[4];
  const float* W2 = (const float*)d_in[5];
  const float* b2 = (const float*)d_in[6];

  char* ws = (char*)d_ws;
  size_t off = 0;
  auto alloc = [&](size_t bytes) -> char* {
    char* p = ws + off;
    off += (bytes + 511) & ~(size_t)511;
    return p;
  };
  __bf16* pB[3];
  unsigned char* pF[3];
  for (int m = 0; m < 3; ++m) pB[m] = (__bf16*)alloc((size_t)NP * D * 2);
  for (int m = 0; m < 3; ++m) pF[m] = (unsigned char*)alloc((size_t)NP * D);
  __bf16* w1b  = (__bf16*)alloc((size_t)D * D * 2);
  __bf16* w2b  = (__bf16*)alloc((size_t)D * D * 2);
  __bf16* zb   = (__bf16*)alloc((size_t)NP * D * 2);
  __bf16* hB   = (__bf16*)alloc((size_t)NP * D * 2);
  float*  praw = (float*) alloc((size_t)NP * D * 4);
  float*  Sv   = (float*) alloc((size_t)6 * NP * 4);
  float*  dg   = (float*) alloc((size_t)5 * NP * 4);

  hipMemsetAsync(Sv, 0, (size_t)6 * NP * 4, stream);
  hipMemsetAsync(d_out, 0, sizeof(float), stream);

  cast_kernel<<<64, 256, 0, stream>>>(W1, w1b, D * D);
  cast_kernel<<<64, 256, 0, stream>>>(W2, w2b, D * D);

  for (int m = 0; m < 3; ++m) {
    cast_kernel<<<2500, 256, 0, stream>>>(z[m], zb, N_ROWS * D);
    dim3 g(PT, 2);
    proj_kernel<0><<<g, 256, 0, stream>>>(zb, w1b, b1, (void*)hB);
    proj_kernel<1><<<g, 256, 0, stream>>>(hB, w2b, b2, (void*)praw);
    norm_kernel<<<NP / 4, 256, 0, stream>>>(praw, pB[m], pF[m]);
  }

  gram_kernel<<<NWGG, 256, 0, stream>>>(pF[0], pF[1], pF[2], Sv);
  diag_kernel<<<2500, 256, 0, stream>>>(pB[0], pB[1], pB[2], dg);
  loss_kernel<<<64, 256, 0, stream>>>(Sv, dg, (float*)d_out);
}